// Round 24
// baseline (471.287 us; speedup 1.0000x reference)
//
#include <hip/hip_runtime.h>
#include <hip/hip_bf16.h>

typedef unsigned short u16;
typedef unsigned int u32;
typedef __attribute__((ext_vector_type(8))) short s16x8;
typedef __attribute__((ext_vector_type(4))) float f32x4;

constexpr int CD    = 180;
constexpr int CP    = 192;              // K-padded channel count
constexpr int BATCH = 4;
constexpr int RES   = 128;
constexpr int LSZ   = RES * RES;        // 16384
constexpr int NHEAD = 6;
constexpr int DH    = 30;
constexpr int NTOK  = 64;
constexpr int NWIN  = 1024;
constexpr int MROWS = NWIN * NTOK;      // 65536
constexpr size_t S192 = (size_t)MROWS * CP;
constexpr size_t S180 = (size_t)MROWS * CD;
constexpr size_t XSZ  = (size_t)BATCH * CD * LSZ;

__device__ __forceinline__ float b2f(u16 u) { return __uint_as_float(((u32)u) << 16); }
__device__ __forceinline__ u16 f2b(float f) {
    __hip_bfloat16 h = __float2bfloat16(f);
    return *reinterpret_cast<u16*>(&h);
}
// fast GELU: sigmoid form x*sigma(1.702x)
__device__ __forceinline__ float gelu_f(float x) {
    float s = __builtin_amdgcn_rcpf(1.f + __expf(-1.702f * x));
    return x * s;
}

// ---------------- merged weight prep: 8 fragment-major jobs in one launch
struct PrepArgs {
    const float *s0, *s1, *s2, *s3, *s4, *s5, *s6, *s7;
    u16* dst;   // base of contiguous dst region (wg_e)
};
__device__ __forceinline__ void do_frag(const float* __restrict__ src,
        u16* __restrict__ dst, int N, int K, int nks, int li) {
    int e = li & 7, lr = (li >> 3) & 15, lk = (li >> 7) & 3, rest = li >> 9;
    int ks = rest % nks, ct = rest / nks;
    int n = ct * 16 + lr, k = ks * 32 + lk * 8 + e;
    float v = (n < N && k < K) ? src[n * K + k] : 0.f;
    dst[li] = f2b(v);
}
// proj weights: K=384 split layout (oute cols 0-191 pad, outb 192-383 pad)
__device__ __forceinline__ void do_frag_proj(const float* __restrict__ src,
        u16* __restrict__ dst, int li) {
    int e = li & 7, lr = (li >> 3) & 15, lk = (li >> 7) & 3, rest = li >> 9;
    int ks = rest % 12, ct = rest / 12;
    int n = ct * 16 + lr, k = ks * 32 + lk * 8 + e;
    int khalf = k & 191;
    int ksrc = (k < 192) ? khalf : 180 + khalf;
    float v = (n < 180 && khalf < 180) ? src[n * 360 + ksrc] : 0.f;
    dst[li] = f2b(v);
}
__global__ __launch_bounds__(256) void prep_all(PrepArgs pa) {
    int bid = blockIdx.x, t = threadIdx.x;
    if (bid < 144)       do_frag(pa.s0, pa.dst,          180, 180,  6, (bid       ) * 256 + t);
    else if (bid < 288)  do_frag(pa.s1, pa.dst + 36864,  180, 180,  6, (bid - 144 ) * 256 + t);
    else if (bid < 576)  do_frag_proj(pa.s2, pa.dst + 73728,           (bid - 288 ) * 256 + t);
    else if (bid < 864)  do_frag_proj(pa.s3, pa.dst + 147456,          (bid - 576 ) * 256 + t);
    else if (bid < 1440) do_frag(pa.s4, pa.dst + 221184, 720, 180,  6, (bid - 864 ) * 256 + t);
    else if (bid < 2016) do_frag(pa.s5, pa.dst + 368640, 720, 180,  6, (bid - 1440) * 256 + t);
    else if (bid < 2592) do_frag(pa.s6, pa.dst + 516096, 180, 720, 24, (bid - 2016) * 256 + t);
    else                 do_frag(pa.s7, pa.dst + 663552, 180, 720, 24, (bid - 2592) * 256 + t);
}

// ---------------- merged qkv weight prep (e and b)
__global__ __launch_bounds__(256) void prep_wqkv2(
        const float* __restrict__ we, const float* __restrict__ be,
        const float* __restrict__ wb, const float* __restrict__ bb,
        u16* __restrict__ wp_base, float* __restrict__ bp_base) {
    int gi = blockIdx.x * 256 + threadIdx.x;
    int flag = gi >= 576 * 192;
    int i = flag ? gi - 576 * 192 : gi;
    if (i >= 576 * 192) return;
    const float* w = flag ? wb : we;
    const float* bsrc = flag ? bb : be;
    u16* wp = wp_base + (size_t)flag * (576 * 192);
    float* bp = bp_base + flag * 576;
    int e = i & 7, lr = (i >> 3) & 15, lk = (i >> 7) & 3, rest = i >> 9;
    int ks = rest % 6, rest2 = rest / 6;
    int ct = rest2 % 6, head = rest2 / 6;
    int rr = ct * 16 + lr;
    int sec = rr >> 5, dd = rr & 31;
    int srow = sec * 180 + head * 30 + dd;
    int k = ks * 32 + lk * 8 + e;
    float scale = (sec == 0) ? 0.18257418583505536f : 1.f;
    float v = (dd < 30 && k < 180) ? w[srow * 180 + k] * scale : 0.f;
    wp[i] = f2b(v);
    if (ks == 0 && lk == 0 && e == 0)
        bp[head * 96 + rr] = (dd < 30) ? bsrc[srow] * scale : 0.f;
}

// ---------------- merged MFMA attention (e and b) + fused LN1 + sigmoid gate
__global__ __launch_bounds__(256) void attn2(
    const float* __restrict__ e_f, const float* __restrict__ b_f,
    const float* __restrict__ g1e, const float* __restrict__ be1e,
    const float* __restrict__ g1b, const float* __restrict__ be1b,
    const u16* __restrict__ wq_base,
    const float* __restrict__ bq_base, const float* __restrict__ rpb,
    const u16* __restrict__ wg_base, const float* __restrict__ gbias_e,
    const float* __restrict__ gbias_b, u16* __restrict__ sig_base,
    u16* __restrict__ out_base) {
    __shared__ __align__(16) char smem[28448];
    u16*   ews  = (u16*)smem;                 // 64*200*2 = 25600 B (staging, dies)
    u16*   Qs   = (u16*)smem;                 // 64*36*2  =  4608
    u16*   Ks   = (u16*)(smem + 4608);
    u16*   Vt   = (u16*)(smem + 9216);        // 32*72*2  =  4608
    u16*   Pb   = (u16*)(smem + 13824);       // 64*72*2  =  9216
    float* rpbs = (float*)(smem + 23040);     // 1350*4   =  5400

    int bid = blockIdx.x;
    int flag = bid >> 10;
    int widx = bid & 1023;
    const float* srcf = flag ? b_f : e_f;
    const float* g1 = flag ? g1b : g1e;
    const float* be1 = flag ? be1b : be1e;
    const u16* Wq = wq_base + (size_t)flag * (576 * 192);
    const float* Bq = bq_base + flag * 576;
    u16* outp = out_base + (size_t)flag * S180;

    int bb = widx >> 8;
    int wrem = widx & 255;
    int wh = wrem >> 4, ww = wrem & 15;
    bool edge = (wh == 15) || (ww == 15);
    int t = threadIdx.x;
    size_t wbase = (size_t)widx * NTOK * CD;

    // ---- fused LN1: stage rolled window fp32 -> bf16 into ews
    for (int i = t; i < NTOK * CD; i += 256) {
        int c = i >> 6, pos = i & 63;
        int sh = ((wh << 3) + (pos >> 3) + 4) & 127;
        int sw = ((ww << 3) + (pos & 7) + 4) & 127;
        ews[pos * 200 + c] = f2b(srcf[(((size_t)bb * CD + c) << 14) + (sh << 7) + sw]);
    }
    for (int i = t; i < 64 * 12; i += 256) {
        int pos = i / 12, c = 180 + i % 12;
        ews[pos * 200 + c] = 0;
    }
    __syncthreads();
    // per-row stats + in-place normalize (4 lanes per row, own 45-col segments)
    {
        int pos = t >> 2, sub = t & 3;
        float s = 0.f, ss = 0.f;
        for (int k = 0; k < 45; ++k) {
            float v = b2f(ews[pos * 200 + sub * 45 + k]);
            s += v; ss += v * v;
        }
        s += __shfl_xor(s, 1); ss += __shfl_xor(ss, 1);
        s += __shfl_xor(s, 2); ss += __shfl_xor(ss, 2);
        float mean = s * (1.f / CD);
        float rstd = rsqrtf(ss * (1.f / CD) - mean * mean + 1e-5f);
        for (int k = 0; k < 45; ++k) {
            int c = sub * 45 + k;
            float v = b2f(ews[pos * 200 + c]);
            ews[pos * 200 + c] = f2b((v - mean) * rstd * g1[c] + be1[c]);
        }
    }
    __syncthreads();

    int wave = t >> 6, lane = t & 63, lr = lane & 15, lk = lane >> 4;
    s16x8 a[6];
    #pragma unroll
    for (int ks = 0; ks < 6; ++ks)
        a[ks] = *(const s16x8*)&ews[(wave * 16 + lr) * 200 + ks * 32 + lk * 8];
    __syncthreads();   // all waves done reading ews; region reusable

    for (int i = t; i < 1350; i += 256) rpbs[i] = rpb[i];  // visible after next barrier

    // ---- fused gate: ct triples, 3 independent accumulators (3-wide MFMA ILP)
    {
        const u16* Wg = wg_base + flag * 36864;
        const float* gbias = flag ? gbias_b : gbias_e;
        u16* sig = sig_base + (size_t)flag * S192;
        for (int ctp = 0; ctp < 4; ++ctp) {
            int ctb = ctp * 3;
            f32x4 acc[3];
            #pragma unroll
            for (int q = 0; q < 3; ++q) acc[q] = (f32x4){0.f, 0.f, 0.f, 0.f};
            #pragma unroll
            for (int ks = 0; ks < 6; ++ks) {
                #pragma unroll
                for (int q = 0; q < 3; ++q) {
                    s16x8 b = *(const s16x8*)&Wg[((size_t)((ctb + q) * 6 + ks) * 64 + lane) * 8];
                    acc[q] = __builtin_amdgcn_mfma_f32_16x16x32_bf16(a[ks], b, acc[q], 0, 0, 0);
                }
            }
            #pragma unroll
            for (int q = 0; q < 3; ++q) {
                int c = (ctb + q) * 16 + lr;
                if (c < CD) {
                    float bbv = gbias[c];
                    #pragma unroll
                    for (int j = 0; j < 4; ++j) {
                        int rowm = widx * 64 + wave * 16 + lk * 4 + j;
                        float v = acc[q][j] + bbv;
                        v = __builtin_amdgcn_rcpf(1.f + __expf(-v));
                        sig[(size_t)rowm * CP + c] = f2b(v);
                    }
                }
            }
        }
    }

    for (int h = 0; h < NHEAD; ++h) {
        // ---- QKV: ct triples, 3 independent accumulators (per-ct sec)
        #pragma unroll
        for (int ctp = 0; ctp < 2; ++ctp) {
            int ctb = ctp * 3;
            f32x4 acc[3];
            #pragma unroll
            for (int q = 0; q < 3; ++q) acc[q] = (f32x4){0.f, 0.f, 0.f, 0.f};
            #pragma unroll
            for (int ks = 0; ks < 6; ++ks) {
                #pragma unroll
                for (int q = 0; q < 3; ++q) {
                    s16x8 b = *(const s16x8*)&Wq[(((size_t)(h * 6 + ctb + q) * 6 + ks) * 64 + lane) * 8];
                    acc[q] = __builtin_amdgcn_mfma_f32_16x16x32_bf16(a[ks], b, acc[q], 0, 0, 0);
                }
            }
            #pragma unroll
            for (int q = 0; q < 3; ++q) {
                int ct = ctb + q;
                int sec = ct >> 1;
                int dd = ((ct & 1) << 4) + lr;
                float bbv = Bq[h * 96 + ct * 16 + lr];
                #pragma unroll
                for (int j = 0; j < 4; ++j) {
                    int tok = wave * 16 + lk * 4 + j;
                    float v = acc[q][j] + bbv;
                    if (sec == 0)      Qs[tok * 36 + dd] = f2b(v);
                    else if (sec == 1) Ks[tok * 36 + dd] = f2b(v);
                    else               Vt[dd * 72 + tok] = f2b(v);
                }
            }
        }
        __syncthreads();
        f32x4 sv[4];
        {
            s16x8 qa = *(const s16x8*)&Qs[(wave * 16 + lr) * 36 + lk * 8];
            #pragma unroll
            for (int ct = 0; ct < 4; ++ct) {
                s16x8 kb = *(const s16x8*)&Ks[(ct * 16 + lr) * 36 + lk * 8];
                f32x4 z = {0.f, 0.f, 0.f, 0.f};
                sv[ct] = __builtin_amdgcn_mfma_f32_16x16x32_bf16(qa, kb, z, 0, 0, 0);
            }
            #pragma unroll
            for (int ct = 0; ct < 4; ++ct) {
                int sj = ct * 16 + lr;
                int jh = sj >> 3, jw = sj & 7;
                #pragma unroll
                for (int j = 0; j < 4; ++j) {
                    int si = wave * 16 + lk * 4 + j;
                    int ih = si >> 3, iw = si & 7;
                    float v = sv[ct][j] + rpbs[((ih - jh + 7) * 15 + (iw - jw + 7)) * 6 + h];
                    if (edge) {
                        int hri = (wh << 3) + ih, wri = (ww << 3) + iw;
                        int hrj = (wh << 3) + jh, wrj = (ww << 3) + jw;
                        int ri = (hri < 120 ? 0 : (hri < 124 ? 1 : 2)) * 3 + (wri < 120 ? 0 : (wri < 124 ? 1 : 2));
                        int rj = (hrj < 120 ? 0 : (hrj < 124 ? 1 : 2)) * 3 + (wrj < 120 ? 0 : (wrj < 124 ? 1 : 2));
                        if (ri != rj) v -= 100.f;
                    }
                    sv[ct][j] = v;
                }
            }
        }
        __syncthreads();
        #pragma unroll
        for (int j = 0; j < 4; ++j) {
            float mx = fmaxf(fmaxf(sv[0][j], sv[1][j]), fmaxf(sv[2][j], sv[3][j]));
            mx = fmaxf(mx, __shfl_xor(mx, 1));
            mx = fmaxf(mx, __shfl_xor(mx, 2));
            mx = fmaxf(mx, __shfl_xor(mx, 4));
            mx = fmaxf(mx, __shfl_xor(mx, 8));
            float e0 = __expf(sv[0][j] - mx);
            float e1 = __expf(sv[1][j] - mx);
            float e2 = __expf(sv[2][j] - mx);
            float e3 = __expf(sv[3][j] - mx);
            float sm = e0 + e1 + e2 + e3;
            sm += __shfl_xor(sm, 1);
            sm += __shfl_xor(sm, 2);
            sm += __shfl_xor(sm, 4);
            sm += __shfl_xor(sm, 8);
            float inv = 1.f / sm;
            int row = wave * 16 + lk * 4 + j;
            Pb[row * 72 +      lr] = f2b(e0 * inv);
            Pb[row * 72 + 16 + lr] = f2b(e1 * inv);
            Pb[row * 72 + 32 + lr] = f2b(e2 * inv);
            Pb[row * 72 + 48 + lr] = f2b(e3 * inv);
        }
        __syncthreads();
        {
            s16x8 pa0 = *(const s16x8*)&Pb[(wave * 16 + lr) * 72 + lk * 8];
            s16x8 pa1 = *(const s16x8*)&Pb[(wave * 16 + lr) * 72 + 32 + lk * 8];
            #pragma unroll
            for (int ct = 0; ct < 2; ++ct) {
                f32x4 acc = {0.f, 0.f, 0.f, 0.f};
                s16x8 vb0 = *(const s16x8*)&Vt[(ct * 16 + lr) * 72 + lk * 8];
                s16x8 vb1 = *(const s16x8*)&Vt[(ct * 16 + lr) * 72 + 32 + lk * 8];
                acc = __builtin_amdgcn_mfma_f32_16x16x32_bf16(pa0, vb0, acc, 0, 0, 0);
                acc = __builtin_amdgcn_mfma_f32_16x16x32_bf16(pa1, vb1, acc, 0, 0, 0);
                int dd = ct * 16 + lr;
                if (dd < DH) {
                    #pragma unroll
                    for (int j = 0; j < 4; ++j) {
                        int tok = wave * 16 + lk * 4 + j;
                        outp[wbase + (size_t)tok * CD + h * DH + dd] = f2b(acc[j]);
                    }
                }
            }
        }
        __syncthreads();
    }
}

// ---------------- FUSED proj + addback + LN2 + MLP (one block = 64 windowed rows)
// __launch_bounds__(256, 3): force combined VGPR+AGPR <= 170 so 3 waves/SIMD fit
// (occupancy experiment; phase A a[12] is rematerializable).
__global__ __launch_bounds__(256, 3) void proj_mlp(
    const u16* __restrict__ oute, const u16* __restrict__ outb,
    const u16* __restrict__ sig_base, const u16* __restrict__ wp_base,
    const float* __restrict__ bias_e, const float* __restrict__ bias_b,
    const float* __restrict__ e_f, const float* __restrict__ b_f,
    const float* __restrict__ g2e, const float* __restrict__ be2e,
    const float* __restrict__ g2b, const float* __restrict__ be2b,
    const u16* __restrict__ w1_base, const float* __restrict__ b1_e,
    const float* __restrict__ b1_b, const u16* __restrict__ w2_base,
    const float* __restrict__ b2_e, const float* __restrict__ b2_b,
    float2* __restrict__ stats_base, float* __restrict__ xout_base) {
    __shared__ __align__(16) u16 Xs[6 * 4 * 64 * 8];    // 24576 B
    __shared__ __align__(16) u16 Hid[4 * 4 * 64 * 8];   // 16384 B  (total 40960)
    int bid = blockIdx.x, t = threadIdx.x;
    int flag = bid >> 10;
    int rb = bid & 1023;
    const u16* sig = sig_base + (size_t)flag * S192;
    const u16* Wb = wp_base + flag * (192 * 384);
    const float* bias = flag ? bias_b : bias_e;
    const float* src = flag ? b_f : e_f;
    const float* gamma = flag ? g2b : g2e;
    const float* beta2 = flag ? be2b : be2e;
    const u16* W1p = w1_base + (size_t)flag * (768 * 192);
    const u16* W2p = w2_base + (size_t)flag * (192 * 768);
    const float* b1 = flag ? b1_b : b1_e;
    const float* b2v = flag ? b2_b : b2_e;
    float2* stats = stats_base + (size_t)flag * MROWS;
    float* xout = xout_base + (size_t)flag * XSZ;
    size_t rb64 = (size_t)rb * 64;
    int wave = t >> 6, lane = t & 63, lr = lane & 15, lk = lane >> 4;
    int row = wave * 16 + lr;

    // spatial base address (same hh for j=0..3; w contiguous, wrap-safe)
    int rowm0 = (int)rb64 + wave * 16 + lk * 4;
    int win0 = rowm0 >> 6, pos0 = rowm0 & 63;
    int bb0 = win0 >> 8, whh0 = (win0 >> 4) & 15, www0 = win0 & 15;
    int hh0 = (((whh0 << 3) + (pos0 >> 3)) + 4) & 127;
    int w200 = (((www0 << 3) + (pos0 & 7)) + 4) & 127;
    size_t sbase = (((size_t)bb0 * CD) << 14) + (hh0 << 7) + w200;

    // ======== Phase A pass 1: proj (ct triples) + residual -> Xs + stats ====
    float s0 = 0.f, s1 = 0.f, s2 = 0.f, s3 = 0.f;
    float q0 = 0.f, q1 = 0.f, q2 = 0.f, q3 = 0.f;
    {
        const u16* oe_row = oute + (rb64 + row) * (size_t)CD;
        const u16* ob_row = outb + (rb64 + row) * (size_t)CD;
        const u16* sg_row = sig + (rb64 + row) * (size_t)CP;
        s16x8 a[12];
        #pragma unroll
        for (int ks = 0; ks < 12; ++ks) {
            int koff = (ks >= 6 ? ks - 6 : ks) * 32 + lk * 8;   // 0..184
            const u16* sp = (ks < 6) ? oe_row : ob_row;
            s16x8 v = *(const s16x8*)&sp[koff];
            s16x8 g = *(const s16x8*)&sg_row[koff];
            s16x8 r;
            #pragma unroll
            for (int e = 0; e < 8; ++e) {
                float p = b2f((u16)v[e]) * b2f((u16)g[e]);
                if ((ks == 5 || ks == 11) && (koff + e >= 180)) p = 0.f;
                r[e] = (short)f2b(p);
            }
            a[ks] = r;
        }
        #pragma unroll
        for (int ctp = 0; ctp < 4; ++ctp) {
            int ctb = ctp * 3;
            f32x4 acc[3];
            #pragma unroll
            for (int q = 0; q < 3; ++q) acc[q] = (f32x4){0.f, 0.f, 0.f, 0.f};
            #pragma unroll
            for (int ks = 0; ks < 12; ++ks) {
                #pragma unroll
                for (int q = 0; q < 3; ++q) {
                    s16x8 b = *(const s16x8*)&Wb[((size_t)((ctb + q) * 12 + ks) * 64 + lane) * 8];
                    acc[q] = __builtin_amdgcn_mfma_f32_16x16x32_bf16(a[ks], b, acc[q], 0, 0, 0);
                }
            }
            #pragma unroll
            for (int q = 0; q < 3; ++q) {
                int c = (ctb + q) * 16 + lr;
                int sks = c >> 5, slk = (c >> 3) & 3, e = c & 7;
                int xb = ((sks * 4 + wave) * 64) + (slk * 16 + lk * 4);
                if (c < CD) {
                    float bv = bias[c];
                    size_t idx0 = sbase + ((size_t)c << 14);
                    float4 s4 = *(const float4*)&src[idx0];
                    float x0 = s4.x + acc[q][0] + bv;
                    float x1 = s4.y + acc[q][1] + bv;
                    float x2 = s4.z + acc[q][2] + bv;
                    float x3 = s4.w + acc[q][3] + bv;
                    Xs[(xb + 0) * 8 + e] = f2b(x0);
                    Xs[(xb + 1) * 8 + e] = f2b(x1);
                    Xs[(xb + 2) * 8 + e] = f2b(x2);
                    Xs[(xb + 3) * 8 + e] = f2b(x3);
                    s0 += x0; q0 += x0 * x0;
                    s1 += x1; q1 += x1 * x1;
                    s2 += x2; q2 += x2 * x2;
                    s3 += x3; q3 += x3 * x3;
                } else {
                    #pragma unroll
                    for (int j = 0; j < 4; ++j) Xs[(xb + j) * 8 + e] = 0;
                }
            }
        }
    }
    // reduce row sums over the 16-lane lr group
    #pragma unroll
    for (int m = 1; m < 16; m <<= 1) {
        s0 += __shfl_xor(s0, m); q0 += __shfl_xor(q0, m);
        s1 += __shfl_xor(s1, m); q1 += __shfl_xor(q1, m);
        s2 += __shfl_xor(s2, m); q2 += __shfl_xor(q2, m);
        s3 += __shfl_xor(s3, m); q3 += __shfl_xor(q3, m);
    }
    float mean[4], rstd[4];
    mean[0] = s0 * (1.f / CD); rstd[0] = rsqrtf(q0 * (1.f / CD) - mean[0] * mean[0] + 1e-5f);
    mean[1] = s1 * (1.f / CD); rstd[1] = rsqrtf(q1 * (1.f / CD) - mean[1] * mean[1] + 1e-5f);
    mean[2] = s2 * (1.f / CD); rstd[2] = rsqrtf(q2 * (1.f / CD) - mean[2] * mean[2] + 1e-5f);
    mean[3] = s3 * (1.f / CD); rstd[3] = rsqrtf(q3 * (1.f / CD) - mean[3] * mean[3] + 1e-5f);
    // stash per-row (mean, rstd) for the epilogue (visible after __syncthreads)
    if (lr == 0) {
        #pragma unroll
        for (int j = 0; j < 4; ++j)
            stats[rb64 + wave * 16 + lk * 4 + j] = make_float2(mean[j], rstd[j]);
    }

    // ======== Phase A pass 2: normalize Xs in place (own elements only) =====
    #pragma unroll
    for (int ct = 0; ct < 12; ++ct) {
        int c = ct * 16 + lr;
        if (c < CD) {
            float g = gamma[c], be = beta2[c];
            int sks = c >> 5, slk = (c >> 3) & 3, e = c & 7;
            int xb = ((sks * 4 + wave) * 64) + (slk * 16 + lk * 4);
            #pragma unroll
            for (int j = 0; j < 4; ++j) {
                float xv = b2f(Xs[(xb + j) * 8 + e]);
                Xs[(xb + j) * 8 + e] = f2b((xv - mean[j]) * rstd[j] * g + be);
            }
        }
    }
    __syncthreads();

    // ======== Phase B: MLP ========
    f32x4 acc2[3][4];
    #pragma unroll
    for (int c = 0; c < 3; ++c)
        #pragma unroll
        for (int m = 0; m < 4; ++m) acc2[c][m] = (f32x4){0.f, 0.f, 0.f, 0.f};

    for (int ch = 0; ch < 6; ++ch) {
        // ---- GEMM1: one ctg at a time (low transient regs; 4-wide m-ILP)
        #pragma unroll 2
        for (int cti = 0; cti < 2; ++cti) {
            int ctg = ch * 8 + wave * 2 + cti;
            f32x4 hd[4];
            #pragma unroll
            for (int m = 0; m < 4; ++m) hd[m] = (f32x4){0.f, 0.f, 0.f, 0.f};
            #pragma unroll
            for (int ks = 0; ks < 6; ++ks) {
                s16x8 b0 = *(const s16x8*)&W1p[((size_t)(ctg * 6 + ks) * 64 + lane) * 8];
                #pragma unroll
                for (int m = 0; m < 4; ++m) {
                    s16x8 av = *(const s16x8*)&Xs[((ks * 4 + m) * 64 + lane) * 8];  // conflict-free
                    hd[m] = __builtin_amdgcn_mfma_f32_16x16x32_bf16(av, b0, hd[m], 0, 0, 0);
                }
            }
            int hcol = ctg * 16 + lr;
            float bb = (hcol < 720) ? b1[hcol] : 0.f;
            int lcol = wave * 32 + cti * 16 + lr;        // chunk-local col 0..127
            int ksr = lcol >> 5, lkr = (lcol >> 3) & 3, er = lcol & 7;
            #pragma unroll
            for (int m = 0; m < 4; ++m) {
                #pragma unroll
                for (int j = 0; j < 4; ++j) {
                    float v = gelu_f(hd[m][j] + bb);
                    Hid[(((ksr * 4 + m) * 64) + (lkr * 16 + lk * 4 + j)) * 8 + er] = f2b(v);
                }
            }
        }
        __syncthreads();
        #pragma unroll
        for (int ks = 0; ks < 4; ++ks) {
            int gks = ch * 4 + ks;
            s16x8 av[4];
            #pragma unroll
            for (int m = 0; m < 4; ++m)
                av[m] = *(const s16x8*)&Hid[((ks * 4 + m) * 64 + lane) * 8];    // conflict-free
            #pragma unroll
            for (int ct3 = 0; ct3 < 3; ++ct3) {
                int ctg = wave * 3 + ct3;
                s16x8 b = *(const s16x8*)&W2p[((size_t)(ctg * 24 + gks) * 64 + lane) * 8];
                #pragma unroll
                for (int m = 0; m < 4; ++m)
                    acc2[ct3][m] = __builtin_amdgcn_mfma_f32_16x16x32_bf16(av[m], b, acc2[ct3][m], 0, 0, 0);
            }
        }
        __syncthreads();
    }
    // ---- epilogue: reconstruct x from intact Xs + stats; PURE float4 store
    #pragma unroll
    for (int m = 0; m < 4; ++m) {
        int mm0 = rb * 64 + m * 16 + lk * 4;
        int win = mm0 >> 6, pos1 = mm0 & 63;
        int b = win >> 8, whh = (win >> 4) & 15, www = win & 15;
        int hh = (((whh << 3) + (pos1 >> 3)) + 4) & 127;
        int w20 = (((www << 3) + (pos1 & 7)) + 4) & 127;
        size_t sb2 = (((size_t)b * CD) << 14) + (hh << 7) + w20;
        float2 st[4];
        #pragma unroll
        for (int j = 0; j < 4; ++j)
            st[j] = stats[rb64 + m * 16 + lk * 4 + j];
        #pragma unroll
        for (int ct3 = 0; ct3 < 3; ++ct3) {
            int cc = (wave * 3 + ct3) * 16 + lr;
            if (cc < CD) {
                float bb = b2v[cc];
                float invgr = __builtin_amdgcn_rcpf(gamma[cc]);
                float becc = beta2[cc];
                int sks = cc >> 5, slk = (cc >> 3) & 3, e = cc & 7;
                size_t idx0 = sb2 + ((size_t)cc << 14);
                float4 o4;
                float xr[4];
                #pragma unroll
                for (int j = 0; j < 4; ++j) {
                    float xn = b2f(Xs[(((sks * 4 + m) * 64) + (slk * 16 + lk * 4 + j)) * 8 + e]);
                    float invr = __builtin_amdgcn_rcpf(st[j].y);
                    xr[j] = (xn - becc) * invgr * invr + st[j].x;
                }
                o4.x = xr[0] + acc2[ct3][m][0] + bb;
                o4.y = xr[1] + acc2[ct3][m][1] + bb;
                o4.z = xr[2] + acc2[ct3][m][2] + bb;
                o4.w = xr[3] + acc2[ct3][m][3] + bb;
                *(float4*)&xout[idx0] = o4;
            }
        }
    }
}

extern "C" void kernel_launch(void* const* d_in, const int* in_sizes, int n_in,
                              void* d_out, int out_size, void* d_ws, size_t ws_size,
                              hipStream_t stream) {
    const float* e_f = (const float*)d_in[0];
    const float* b_f = (const float*)d_in[1];

    u16* ew   = (u16*)d_ws;                  // (unused, kept for layout)
    u16* bw   = ew + S192;
    u16* sige = bw + S192;
    u16* sigb = sige + S192;
    u16* oute = sigb + S192;
    u16* outb = oute + S180;
    u16* wg_e = outb + S180;                 // contiguous prep region
    u16* wp_e = wg_e + 2 * 36864;
    u16* w1_e = wp_e + 2 * 73728;
    u16* w2_e = w1_e + 2 * 147456;
    u16* wq_e = w2_e + 2 * 147456;           // 2 * 576*192
    float* bq_e = (float*)(wq_e + 2 * 576 * 192);   // 2 * 576
    float2* stats = (float2*)(bq_e + 2 * 576);      // 2 * MROWS float2

    float* xe = (float*)d_out;

    PrepArgs pa;
    pa.s0 = (const float*)d_in[10];
    pa.s1 = (const float*)d_in[12];
    pa.s2 = (const float*)d_in[15];
    pa.s3 = (const float*)d_in[17];
    pa.s4 = (const float*)d_in[23];
    pa.s5 = (const float*)d_in[27];
    pa.s6 = (const float*)d_in[25];
    pa.s7 = (const float*)d_in[29];
    pa.dst = wg_e;
    prep_all<<<3168, 256, 0, stream>>>(pa);
    prep_wqkv2<<<(2 * 576 * 192 + 255) / 256, 256, 0, stream>>>(
        (const float*)d_in[6], (const float*)d_in[7],
        (const float*)d_in[8], (const float*)d_in[9], wq_e, bq_e);

    attn2<<<2 * NWIN, 256, 0, stream>>>(e_f, b_f,
        (const float*)d_in[2], (const float*)d_in[3],
        (const float*)d_in[4], (const float*)d_in[5],
        wq_e, bq_e, (const float*)d_in[14], wg_e,
        (const float*)d_in[11], (const float*)d_in[13], sige, oute);

    proj_mlp<<<2 * MROWS / 64, 256, 0, stream>>>(oute, outb, sige, wp_e,
        (const float*)d_in[16], (const float*)d_in[18], e_f, b_f,
        (const float*)d_in[19], (const float*)d_in[20],
        (const float*)d_in[21], (const float*)d_in[22],
        w1_e, (const float*)d_in[24], (const float*)d_in[28],
        w2_e, (const float*)d_in[26], (const float*)d_in[30], stats, xe);
}

// Round 25
// 457.095 us; speedup vs baseline: 1.0310x; 1.0310x over previous
//
#include <hip/hip_runtime.h>
#include <hip/hip_bf16.h>

typedef unsigned short u16;
typedef unsigned int u32;
typedef __attribute__((ext_vector_type(8))) short s16x8;
typedef __attribute__((ext_vector_type(4))) float f32x4;

constexpr int CD    = 180;
constexpr int CP    = 192;              // K-padded channel count
constexpr int BATCH = 4;
constexpr int RES   = 128;
constexpr int LSZ   = RES * RES;        // 16384
constexpr int NHEAD = 6;
constexpr int DH    = 30;
constexpr int NTOK  = 64;
constexpr int NWIN  = 1024;
constexpr int MROWS = NWIN * NTOK;      // 65536
constexpr size_t S192 = (size_t)MROWS * CP;
constexpr size_t S180 = (size_t)MROWS * CD;
constexpr size_t XSZ  = (size_t)BATCH * CD * LSZ;

__device__ __forceinline__ float b2f(u16 u) { return __uint_as_float(((u32)u) << 16); }
__device__ __forceinline__ u16 f2b(float f) {
    __hip_bfloat16 h = __float2bfloat16(f);
    return *reinterpret_cast<u16*>(&h);
}
// fast GELU: sigmoid form x*sigma(1.702x)
__device__ __forceinline__ float gelu_f(float x) {
    float s = __builtin_amdgcn_rcpf(1.f + __expf(-1.702f * x));
    return x * s;
}

// ---------------- merged weight prep: 8 fragment-major jobs in one launch
struct PrepArgs {
    const float *s0, *s1, *s2, *s3, *s4, *s5, *s6, *s7;
    u16* dst;   // base of contiguous dst region (wg_e)
};
__device__ __forceinline__ void do_frag(const float* __restrict__ src,
        u16* __restrict__ dst, int N, int K, int nks, int li) {
    int e = li & 7, lr = (li >> 3) & 15, lk = (li >> 7) & 3, rest = li >> 9;
    int ks = rest % nks, ct = rest / nks;
    int n = ct * 16 + lr, k = ks * 32 + lk * 8 + e;
    float v = (n < N && k < K) ? src[n * K + k] : 0.f;
    dst[li] = f2b(v);
}
// proj weights: K=384 split layout (oute cols 0-191 pad, outb 192-383 pad)
__device__ __forceinline__ void do_frag_proj(const float* __restrict__ src,
        u16* __restrict__ dst, int li) {
    int e = li & 7, lr = (li >> 3) & 15, lk = (li >> 7) & 3, rest = li >> 9;
    int ks = rest % 12, ct = rest / 12;
    int n = ct * 16 + lr, k = ks * 32 + lk * 8 + e;
    int khalf = k & 191;
    int ksrc = (k < 192) ? khalf : 180 + khalf;
    float v = (n < 180 && khalf < 180) ? src[n * 360 + ksrc] : 0.f;
    dst[li] = f2b(v);
}
__global__ __launch_bounds__(256) void prep_all(PrepArgs pa) {
    int bid = blockIdx.x, t = threadIdx.x;
    if (bid < 144)       do_frag(pa.s0, pa.dst,          180, 180,  6, (bid       ) * 256 + t);
    else if (bid < 288)  do_frag(pa.s1, pa.dst + 36864,  180, 180,  6, (bid - 144 ) * 256 + t);
    else if (bid < 576)  do_frag_proj(pa.s2, pa.dst + 73728,           (bid - 288 ) * 256 + t);
    else if (bid < 864)  do_frag_proj(pa.s3, pa.dst + 147456,          (bid - 576 ) * 256 + t);
    else if (bid < 1440) do_frag(pa.s4, pa.dst + 221184, 720, 180,  6, (bid - 864 ) * 256 + t);
    else if (bid < 2016) do_frag(pa.s5, pa.dst + 368640, 720, 180,  6, (bid - 1440) * 256 + t);
    else if (bid < 2592) do_frag(pa.s6, pa.dst + 516096, 180, 720, 24, (bid - 2016) * 256 + t);
    else                 do_frag(pa.s7, pa.dst + 663552, 180, 720, 24, (bid - 2592) * 256 + t);
}

// ---------------- merged qkv weight prep (e and b)
__global__ __launch_bounds__(256) void prep_wqkv2(
        const float* __restrict__ we, const float* __restrict__ be,
        const float* __restrict__ wb, const float* __restrict__ bb,
        u16* __restrict__ wp_base, float* __restrict__ bp_base) {
    int gi = blockIdx.x * 256 + threadIdx.x;
    int flag = gi >= 576 * 192;
    int i = flag ? gi - 576 * 192 : gi;
    if (i >= 576 * 192) return;
    const float* w = flag ? wb : we;
    const float* bsrc = flag ? bb : be;
    u16* wp = wp_base + (size_t)flag * (576 * 192);
    float* bp = bp_base + flag * 576;
    int e = i & 7, lr = (i >> 3) & 15, lk = (i >> 7) & 3, rest = i >> 9;
    int ks = rest % 6, rest2 = rest / 6;
    int ct = rest2 % 6, head = rest2 / 6;
    int rr = ct * 16 + lr;
    int sec = rr >> 5, dd = rr & 31;
    int srow = sec * 180 + head * 30 + dd;
    int k = ks * 32 + lk * 8 + e;
    float scale = (sec == 0) ? 0.18257418583505536f : 1.f;
    float v = (dd < 30 && k < 180) ? w[srow * 180 + k] * scale : 0.f;
    wp[i] = f2b(v);
    if (ks == 0 && lk == 0 && e == 0)
        bp[head * 96 + rr] = (dd < 30) ? bsrc[srow] * scale : 0.f;
}

// ---------------- merged MFMA attention (e and b) + fused LN1 + sigmoid gate
__global__ __launch_bounds__(256) void attn2(
    const float* __restrict__ e_f, const float* __restrict__ b_f,
    const float* __restrict__ g1e, const float* __restrict__ be1e,
    const float* __restrict__ g1b, const float* __restrict__ be1b,
    const u16* __restrict__ wq_base,
    const float* __restrict__ bq_base, const float* __restrict__ rpb,
    const u16* __restrict__ wg_base, const float* __restrict__ gbias_e,
    const float* __restrict__ gbias_b, u16* __restrict__ sig_base,
    u16* __restrict__ out_base) {
    __shared__ __align__(16) char smem[28448];
    u16*   ews  = (u16*)smem;                 // 64*200*2 = 25600 B (staging, dies)
    u16*   Qs   = (u16*)smem;                 // 64*36*2  =  4608
    u16*   Ks   = (u16*)(smem + 4608);
    u16*   Vt   = (u16*)(smem + 9216);        // 32*72*2  =  4608
    u16*   Pb   = (u16*)(smem + 13824);       // 64*72*2  =  9216
    float* rpbs = (float*)(smem + 23040);     // 1350*4   =  5400

    int bid = blockIdx.x;
    int flag = bid >> 10;
    int widx = bid & 1023;
    const float* srcf = flag ? b_f : e_f;
    const float* g1 = flag ? g1b : g1e;
    const float* be1 = flag ? be1b : be1e;
    const u16* Wq = wq_base + (size_t)flag * (576 * 192);
    const float* Bq = bq_base + flag * 576;
    u16* outp = out_base + (size_t)flag * S180;

    int bb = widx >> 8;
    int wrem = widx & 255;
    int wh = wrem >> 4, ww = wrem & 15;
    bool edge = (wh == 15) || (ww == 15);
    int t = threadIdx.x;
    size_t wbase = (size_t)widx * NTOK * CD;

    // ---- fused LN1: stage rolled window fp32 -> bf16 into ews
    for (int i = t; i < NTOK * CD; i += 256) {
        int c = i >> 6, pos = i & 63;
        int sh = ((wh << 3) + (pos >> 3) + 4) & 127;
        int sw = ((ww << 3) + (pos & 7) + 4) & 127;
        ews[pos * 200 + c] = f2b(srcf[(((size_t)bb * CD + c) << 14) + (sh << 7) + sw]);
    }
    for (int i = t; i < 64 * 12; i += 256) {
        int pos = i / 12, c = 180 + i % 12;
        ews[pos * 200 + c] = 0;
    }
    __syncthreads();
    // per-row stats + in-place normalize (4 lanes per row, own 45-col segments)
    {
        int pos = t >> 2, sub = t & 3;
        float s = 0.f, ss = 0.f;
        for (int k = 0; k < 45; ++k) {
            float v = b2f(ews[pos * 200 + sub * 45 + k]);
            s += v; ss += v * v;
        }
        s += __shfl_xor(s, 1); ss += __shfl_xor(ss, 1);
        s += __shfl_xor(s, 2); ss += __shfl_xor(ss, 2);
        float mean = s * (1.f / CD);
        float rstd = rsqrtf(ss * (1.f / CD) - mean * mean + 1e-5f);
        for (int k = 0; k < 45; ++k) {
            int c = sub * 45 + k;
            float v = b2f(ews[pos * 200 + c]);
            ews[pos * 200 + c] = f2b((v - mean) * rstd * g1[c] + be1[c]);
        }
    }
    __syncthreads();

    int wave = t >> 6, lane = t & 63, lr = lane & 15, lk = lane >> 4;
    s16x8 a[6];
    #pragma unroll
    for (int ks = 0; ks < 6; ++ks)
        a[ks] = *(const s16x8*)&ews[(wave * 16 + lr) * 200 + ks * 32 + lk * 8];
    __syncthreads();   // all waves done reading ews; region reusable

    for (int i = t; i < 1350; i += 256) rpbs[i] = rpb[i];  // visible after next barrier

    // ---- fused gate: ct triples, 3 independent accumulators (3-wide MFMA ILP)
    {
        const u16* Wg = wg_base + flag * 36864;
        const float* gbias = flag ? gbias_b : gbias_e;
        u16* sig = sig_base + (size_t)flag * S192;
        for (int ctp = 0; ctp < 4; ++ctp) {
            int ctb = ctp * 3;
            f32x4 acc[3];
            #pragma unroll
            for (int q = 0; q < 3; ++q) acc[q] = (f32x4){0.f, 0.f, 0.f, 0.f};
            #pragma unroll
            for (int ks = 0; ks < 6; ++ks) {
                #pragma unroll
                for (int q = 0; q < 3; ++q) {
                    s16x8 b = *(const s16x8*)&Wg[((size_t)((ctb + q) * 6 + ks) * 64 + lane) * 8];
                    acc[q] = __builtin_amdgcn_mfma_f32_16x16x32_bf16(a[ks], b, acc[q], 0, 0, 0);
                }
            }
            #pragma unroll
            for (int q = 0; q < 3; ++q) {
                int c = (ctb + q) * 16 + lr;
                if (c < CD) {
                    float bbv = gbias[c];
                    #pragma unroll
                    for (int j = 0; j < 4; ++j) {
                        int rowm = widx * 64 + wave * 16 + lk * 4 + j;
                        float v = acc[q][j] + bbv;
                        v = __builtin_amdgcn_rcpf(1.f + __expf(-v));
                        sig[(size_t)rowm * CP + c] = f2b(v);
                    }
                }
            }
        }
    }

    for (int h = 0; h < NHEAD; ++h) {
        // ---- QKV: ct triples, 3 independent accumulators (per-ct sec)
        #pragma unroll
        for (int ctp = 0; ctp < 2; ++ctp) {
            int ctb = ctp * 3;
            f32x4 acc[3];
            #pragma unroll
            for (int q = 0; q < 3; ++q) acc[q] = (f32x4){0.f, 0.f, 0.f, 0.f};
            #pragma unroll
            for (int ks = 0; ks < 6; ++ks) {
                #pragma unroll
                for (int q = 0; q < 3; ++q) {
                    s16x8 b = *(const s16x8*)&Wq[(((size_t)(h * 6 + ctb + q) * 6 + ks) * 64 + lane) * 8];
                    acc[q] = __builtin_amdgcn_mfma_f32_16x16x32_bf16(a[ks], b, acc[q], 0, 0, 0);
                }
            }
            #pragma unroll
            for (int q = 0; q < 3; ++q) {
                int ct = ctb + q;
                int sec = ct >> 1;
                int dd = ((ct & 1) << 4) + lr;
                float bbv = Bq[h * 96 + ct * 16 + lr];
                #pragma unroll
                for (int j = 0; j < 4; ++j) {
                    int tok = wave * 16 + lk * 4 + j;
                    float v = acc[q][j] + bbv;
                    if (sec == 0)      Qs[tok * 36 + dd] = f2b(v);
                    else if (sec == 1) Ks[tok * 36 + dd] = f2b(v);
                    else               Vt[dd * 72 + tok] = f2b(v);
                }
            }
        }
        __syncthreads();
        f32x4 sv[4];
        {
            s16x8 qa = *(const s16x8*)&Qs[(wave * 16 + lr) * 36 + lk * 8];
            #pragma unroll
            for (int ct = 0; ct < 4; ++ct) {
                s16x8 kb = *(const s16x8*)&Ks[(ct * 16 + lr) * 36 + lk * 8];
                f32x4 z = {0.f, 0.f, 0.f, 0.f};
                sv[ct] = __builtin_amdgcn_mfma_f32_16x16x32_bf16(qa, kb, z, 0, 0, 0);
            }
            #pragma unroll
            for (int ct = 0; ct < 4; ++ct) {
                int sj = ct * 16 + lr;
                int jh = sj >> 3, jw = sj & 7;
                #pragma unroll
                for (int j = 0; j < 4; ++j) {
                    int si = wave * 16 + lk * 4 + j;
                    int ih = si >> 3, iw = si & 7;
                    float v = sv[ct][j] + rpbs[((ih - jh + 7) * 15 + (iw - jw + 7)) * 6 + h];
                    if (edge) {
                        int hri = (wh << 3) + ih, wri = (ww << 3) + iw;
                        int hrj = (wh << 3) + jh, wrj = (ww << 3) + jw;
                        int ri = (hri < 120 ? 0 : (hri < 124 ? 1 : 2)) * 3 + (wri < 120 ? 0 : (wri < 124 ? 1 : 2));
                        int rj = (hrj < 120 ? 0 : (hrj < 124 ? 1 : 2)) * 3 + (wrj < 120 ? 0 : (wrj < 124 ? 1 : 2));
                        if (ri != rj) v -= 100.f;
                    }
                    sv[ct][j] = v;
                }
            }
        }
        __syncthreads();
        #pragma unroll
        for (int j = 0; j < 4; ++j) {
            float mx = fmaxf(fmaxf(sv[0][j], sv[1][j]), fmaxf(sv[2][j], sv[3][j]));
            mx = fmaxf(mx, __shfl_xor(mx, 1));
            mx = fmaxf(mx, __shfl_xor(mx, 2));
            mx = fmaxf(mx, __shfl_xor(mx, 4));
            mx = fmaxf(mx, __shfl_xor(mx, 8));
            float e0 = __expf(sv[0][j] - mx);
            float e1 = __expf(sv[1][j] - mx);
            float e2 = __expf(sv[2][j] - mx);
            float e3 = __expf(sv[3][j] - mx);
            float sm = e0 + e1 + e2 + e3;
            sm += __shfl_xor(sm, 1);
            sm += __shfl_xor(sm, 2);
            sm += __shfl_xor(sm, 4);
            sm += __shfl_xor(sm, 8);
            float inv = 1.f / sm;
            int row = wave * 16 + lk * 4 + j;
            Pb[row * 72 +      lr] = f2b(e0 * inv);
            Pb[row * 72 + 16 + lr] = f2b(e1 * inv);
            Pb[row * 72 + 32 + lr] = f2b(e2 * inv);
            Pb[row * 72 + 48 + lr] = f2b(e3 * inv);
        }
        __syncthreads();
        {
            s16x8 pa0 = *(const s16x8*)&Pb[(wave * 16 + lr) * 72 + lk * 8];
            s16x8 pa1 = *(const s16x8*)&Pb[(wave * 16 + lr) * 72 + 32 + lk * 8];
            #pragma unroll
            for (int ct = 0; ct < 2; ++ct) {
                f32x4 acc = {0.f, 0.f, 0.f, 0.f};
                s16x8 vb0 = *(const s16x8*)&Vt[(ct * 16 + lr) * 72 + lk * 8];
                s16x8 vb1 = *(const s16x8*)&Vt[(ct * 16 + lr) * 72 + 32 + lk * 8];
                acc = __builtin_amdgcn_mfma_f32_16x16x32_bf16(pa0, vb0, acc, 0, 0, 0);
                acc = __builtin_amdgcn_mfma_f32_16x16x32_bf16(pa1, vb1, acc, 0, 0, 0);
                int dd = ct * 16 + lr;
                if (dd < DH) {
                    #pragma unroll
                    for (int j = 0; j < 4; ++j) {
                        int tok = wave * 16 + lk * 4 + j;
                        outp[wbase + (size_t)tok * CD + h * DH + dd] = f2b(acc[j]);
                    }
                }
            }
        }
        __syncthreads();
    }
}

// ---------------- FUSED proj + addback + LN2 + MLP (one block = 64 windowed rows)
// Phase A: ct TRIPLES with 3 independent accumulators; residual; raw bf16 x -> Xs,
// LN stats -> small global stats buffer. Pass2 normalizes Xs in place.
// Phase B: MLP; GEMM1 one ctg at a time (hd[4]). Epilogue reconstructs x; pure store.
__global__ __launch_bounds__(256) void proj_mlp(
    const u16* __restrict__ oute, const u16* __restrict__ outb,
    const u16* __restrict__ sig_base, const u16* __restrict__ wp_base,
    const float* __restrict__ bias_e, const float* __restrict__ bias_b,
    const float* __restrict__ e_f, const float* __restrict__ b_f,
    const float* __restrict__ g2e, const float* __restrict__ be2e,
    const float* __restrict__ g2b, const float* __restrict__ be2b,
    const u16* __restrict__ w1_base, const float* __restrict__ b1_e,
    const float* __restrict__ b1_b, const u16* __restrict__ w2_base,
    const float* __restrict__ b2_e, const float* __restrict__ b2_b,
    float2* __restrict__ stats_base, float* __restrict__ xout_base) {
    __shared__ __align__(16) u16 Xs[6 * 4 * 64 * 8];    // 24576 B
    __shared__ __align__(16) u16 Hid[4 * 4 * 64 * 8];   // 16384 B  (total 40960)
    int bid = blockIdx.x, t = threadIdx.x;
    int flag = bid >> 10;
    int rb = bid & 1023;
    const u16* sig = sig_base + (size_t)flag * S192;
    const u16* Wb = wp_base + flag * (192 * 384);
    const float* bias = flag ? bias_b : bias_e;
    const float* src = flag ? b_f : e_f;
    const float* gamma = flag ? g2b : g2e;
    const float* beta2 = flag ? be2b : be2e;
    const u16* W1p = w1_base + (size_t)flag * (768 * 192);
    const u16* W2p = w2_base + (size_t)flag * (192 * 768);
    const float* b1 = flag ? b1_b : b1_e;
    const float* b2v = flag ? b2_b : b2_e;
    float2* stats = stats_base + (size_t)flag * MROWS;
    float* xout = xout_base + (size_t)flag * XSZ;
    size_t rb64 = (size_t)rb * 64;
    int wave = t >> 6, lane = t & 63, lr = lane & 15, lk = lane >> 4;
    int row = wave * 16 + lr;

    // spatial base address (same hh for j=0..3; w contiguous, wrap-safe)
    int rowm0 = (int)rb64 + wave * 16 + lk * 4;
    int win0 = rowm0 >> 6, pos0 = rowm0 & 63;
    int bb0 = win0 >> 8, whh0 = (win0 >> 4) & 15, www0 = win0 & 15;
    int hh0 = (((whh0 << 3) + (pos0 >> 3)) + 4) & 127;
    int w200 = (((www0 << 3) + (pos0 & 7)) + 4) & 127;
    size_t sbase = (((size_t)bb0 * CD) << 14) + (hh0 << 7) + w200;

    // ======== Phase A pass 1: proj (ct triples) + residual -> Xs + stats ====
    float s0 = 0.f, s1 = 0.f, s2 = 0.f, s3 = 0.f;
    float q0 = 0.f, q1 = 0.f, q2 = 0.f, q3 = 0.f;
    {
        const u16* oe_row = oute + (rb64 + row) * (size_t)CD;
        const u16* ob_row = outb + (rb64 + row) * (size_t)CD;
        const u16* sg_row = sig + (rb64 + row) * (size_t)CP;
        s16x8 a[12];
        #pragma unroll
        for (int ks = 0; ks < 12; ++ks) {
            int koff = (ks >= 6 ? ks - 6 : ks) * 32 + lk * 8;   // 0..184
            const u16* sp = (ks < 6) ? oe_row : ob_row;
            s16x8 v = *(const s16x8*)&sp[koff];
            s16x8 g = *(const s16x8*)&sg_row[koff];
            s16x8 r;
            #pragma unroll
            for (int e = 0; e < 8; ++e) {
                float p = b2f((u16)v[e]) * b2f((u16)g[e]);
                if ((ks == 5 || ks == 11) && (koff + e >= 180)) p = 0.f;
                r[e] = (short)f2b(p);
            }
            a[ks] = r;
        }
        #pragma unroll
        for (int ctp = 0; ctp < 4; ++ctp) {
            int ctb = ctp * 3;
            f32x4 acc[3];
            #pragma unroll
            for (int q = 0; q < 3; ++q) acc[q] = (f32x4){0.f, 0.f, 0.f, 0.f};
            #pragma unroll
            for (int ks = 0; ks < 12; ++ks) {
                #pragma unroll
                for (int q = 0; q < 3; ++q) {
                    s16x8 b = *(const s16x8*)&Wb[((size_t)((ctb + q) * 12 + ks) * 64 + lane) * 8];
                    acc[q] = __builtin_amdgcn_mfma_f32_16x16x32_bf16(a[ks], b, acc[q], 0, 0, 0);
                }
            }
            #pragma unroll
            for (int q = 0; q < 3; ++q) {
                int c = (ctb + q) * 16 + lr;
                int sks = c >> 5, slk = (c >> 3) & 3, e = c & 7;
                int xb = ((sks * 4 + wave) * 64) + (slk * 16 + lk * 4);
                if (c < CD) {
                    float bv = bias[c];
                    size_t idx0 = sbase + ((size_t)c << 14);
                    float4 s4 = *(const float4*)&src[idx0];
                    float x0 = s4.x + acc[q][0] + bv;
                    float x1 = s4.y + acc[q][1] + bv;
                    float x2 = s4.z + acc[q][2] + bv;
                    float x3 = s4.w + acc[q][3] + bv;
                    Xs[(xb + 0) * 8 + e] = f2b(x0);
                    Xs[(xb + 1) * 8 + e] = f2b(x1);
                    Xs[(xb + 2) * 8 + e] = f2b(x2);
                    Xs[(xb + 3) * 8 + e] = f2b(x3);
                    s0 += x0; q0 += x0 * x0;
                    s1 += x1; q1 += x1 * x1;
                    s2 += x2; q2 += x2 * x2;
                    s3 += x3; q3 += x3 * x3;
                } else {
                    #pragma unroll
                    for (int j = 0; j < 4; ++j) Xs[(xb + j) * 8 + e] = 0;
                }
            }
        }
    }
    // reduce row sums over the 16-lane lr group
    #pragma unroll
    for (int m = 1; m < 16; m <<= 1) {
        s0 += __shfl_xor(s0, m); q0 += __shfl_xor(q0, m);
        s1 += __shfl_xor(s1, m); q1 += __shfl_xor(q1, m);
        s2 += __shfl_xor(s2, m); q2 += __shfl_xor(q2, m);
        s3 += __shfl_xor(s3, m); q3 += __shfl_xor(q3, m);
    }
    float mean[4], rstd[4];
    mean[0] = s0 * (1.f / CD); rstd[0] = rsqrtf(q0 * (1.f / CD) - mean[0] * mean[0] + 1e-5f);
    mean[1] = s1 * (1.f / CD); rstd[1] = rsqrtf(q1 * (1.f / CD) - mean[1] * mean[1] + 1e-5f);
    mean[2] = s2 * (1.f / CD); rstd[2] = rsqrtf(q2 * (1.f / CD) - mean[2] * mean[2] + 1e-5f);
    mean[3] = s3 * (1.f / CD); rstd[3] = rsqrtf(q3 * (1.f / CD) - mean[3] * mean[3] + 1e-5f);
    // stash per-row (mean, rstd) for the epilogue (visible after __syncthreads)
    if (lr == 0) {
        #pragma unroll
        for (int j = 0; j < 4; ++j)
            stats[rb64 + wave * 16 + lk * 4 + j] = make_float2(mean[j], rstd[j]);
    }

    // ======== Phase A pass 2: normalize Xs in place (own elements only) =====
    #pragma unroll
    for (int ct = 0; ct < 12; ++ct) {
        int c = ct * 16 + lr;
        if (c < CD) {
            float g = gamma[c], be = beta2[c];
            int sks = c >> 5, slk = (c >> 3) & 3, e = c & 7;
            int xb = ((sks * 4 + wave) * 64) + (slk * 16 + lk * 4);
            #pragma unroll
            for (int j = 0; j < 4; ++j) {
                float xv = b2f(Xs[(xb + j) * 8 + e]);
                Xs[(xb + j) * 8 + e] = f2b((xv - mean[j]) * rstd[j] * g + be);
            }
        }
    }
    __syncthreads();

    // ======== Phase B: MLP ========
    f32x4 acc2[3][4];
    #pragma unroll
    for (int c = 0; c < 3; ++c)
        #pragma unroll
        for (int m = 0; m < 4; ++m) acc2[c][m] = (f32x4){0.f, 0.f, 0.f, 0.f};

    for (int ch = 0; ch < 6; ++ch) {
        // ---- GEMM1: one ctg at a time (low transient regs; 4-wide m-ILP)
        #pragma unroll 2
        for (int cti = 0; cti < 2; ++cti) {
            int ctg = ch * 8 + wave * 2 + cti;
            f32x4 hd[4];
            #pragma unroll
            for (int m = 0; m < 4; ++m) hd[m] = (f32x4){0.f, 0.f, 0.f, 0.f};
            #pragma unroll
            for (int ks = 0; ks < 6; ++ks) {
                s16x8 b0 = *(const s16x8*)&W1p[((size_t)(ctg * 6 + ks) * 64 + lane) * 8];
                #pragma unroll
                for (int m = 0; m < 4; ++m) {
                    s16x8 av = *(const s16x8*)&Xs[((ks * 4 + m) * 64 + lane) * 8];  // conflict-free
                    hd[m] = __builtin_amdgcn_mfma_f32_16x16x32_bf16(av, b0, hd[m], 0, 0, 0);
                }
            }
            int hcol = ctg * 16 + lr;
            float bb = (hcol < 720) ? b1[hcol] : 0.f;
            int lcol = wave * 32 + cti * 16 + lr;        // chunk-local col 0..127
            int ksr = lcol >> 5, lkr = (lcol >> 3) & 3, er = lcol & 7;
            #pragma unroll
            for (int m = 0; m < 4; ++m) {
                #pragma unroll
                for (int j = 0; j < 4; ++j) {
                    float v = gelu_f(hd[m][j] + bb);
                    Hid[(((ksr * 4 + m) * 64) + (lkr * 16 + lk * 4 + j)) * 8 + er] = f2b(v);
                }
            }
        }
        __syncthreads();
        #pragma unroll
        for (int ks = 0; ks < 4; ++ks) {
            int gks = ch * 4 + ks;
            s16x8 av[4];
            #pragma unroll
            for (int m = 0; m < 4; ++m)
                av[m] = *(const s16x8*)&Hid[((ks * 4 + m) * 64 + lane) * 8];    // conflict-free
            #pragma unroll
            for (int ct3 = 0; ct3 < 3; ++ct3) {
                int ctg = wave * 3 + ct3;
                s16x8 b = *(const s16x8*)&W2p[((size_t)(ctg * 24 + gks) * 64 + lane) * 8];
                #pragma unroll
                for (int m = 0; m < 4; ++m)
                    acc2[ct3][m] = __builtin_amdgcn_mfma_f32_16x16x32_bf16(av[m], b, acc2[ct3][m], 0, 0, 0);
            }
        }
        __syncthreads();
    }
    // ---- epilogue: reconstruct x from intact Xs + stats; PURE float4 store
    #pragma unroll
    for (int m = 0; m < 4; ++m) {
        int mm0 = rb * 64 + m * 16 + lk * 4;
        int win = mm0 >> 6, pos1 = mm0 & 63;
        int b = win >> 8, whh = (win >> 4) & 15, www = win & 15;
        int hh = (((whh << 3) + (pos1 >> 3)) + 4) & 127;
        int w20 = (((www << 3) + (pos1 & 7)) + 4) & 127;
        size_t sb2 = (((size_t)b * CD) << 14) + (hh << 7) + w20;
        float2 st[4];
        #pragma unroll
        for (int j = 0; j < 4; ++j)
            st[j] = stats[rb64 + m * 16 + lk * 4 + j];
        #pragma unroll
        for (int ct3 = 0; ct3 < 3; ++ct3) {
            int cc = (wave * 3 + ct3) * 16 + lr;
            if (cc < CD) {
                float bb = b2v[cc];
                float invgr = __builtin_amdgcn_rcpf(gamma[cc]);
                float becc = beta2[cc];
                int sks = cc >> 5, slk = (cc >> 3) & 3, e = cc & 7;
                size_t idx0 = sb2 + ((size_t)cc << 14);
                float4 o4;
                float xr[4];
                #pragma unroll
                for (int j = 0; j < 4; ++j) {
                    float xn = b2f(Xs[(((sks * 4 + m) * 64) + (slk * 16 + lk * 4 + j)) * 8 + e]);
                    float invr = __builtin_amdgcn_rcpf(st[j].y);
                    xr[j] = (xn - becc) * invgr * invr + st[j].x;
                }
                o4.x = xr[0] + acc2[ct3][m][0] + bb;
                o4.y = xr[1] + acc2[ct3][m][1] + bb;
                o4.z = xr[2] + acc2[ct3][m][2] + bb;
                o4.w = xr[3] + acc2[ct3][m][3] + bb;
                *(float4*)&xout[idx0] = o4;
            }
        }
    }
}

extern "C" void kernel_launch(void* const* d_in, const int* in_sizes, int n_in,
                              void* d_out, int out_size, void* d_ws, size_t ws_size,
                              hipStream_t stream) {
    const float* e_f = (const float*)d_in[0];
    const float* b_f = (const float*)d_in[1];

    u16* ew   = (u16*)d_ws;                  // (unused, kept for layout)
    u16* bw   = ew + S192;
    u16* sige = bw + S192;
    u16* sigb = sige + S192;
    u16* oute = sigb + S192;
    u16* outb = oute + S180;
    u16* wg_e = outb + S180;                 // contiguous prep region
    u16* wp_e = wg_e + 2 * 36864;
    u16* w1_e = wp_e + 2 * 73728;
    u16* w2_e = w1_e + 2 * 147456;
    u16* wq_e = w2_e + 2 * 147456;           // 2 * 576*192
    float* bq_e = (float*)(wq_e + 2 * 576 * 192);   // 2 * 576
    float2* stats = (float2*)(bq_e + 2 * 576);      // 2 * MROWS float2

    float* xe = (float*)d_out;

    PrepArgs pa;
    pa.s0 = (const float*)d_in[10];
    pa.s1 = (const float*)d_in[12];
    pa.s2 = (const float*)d_in[15];
    pa.s3 = (const float*)d_in[17];
    pa.s4 = (const float*)d_in[23];
    pa.s5 = (const float*)d_in[27];
    pa.s6 = (const float*)d_in[25];
    pa.s7 = (const float*)d_in[29];
    pa.dst = wg_e;
    prep_all<<<3168, 256, 0, stream>>>(pa);
    prep_wqkv2<<<(2 * 576 * 192 + 255) / 256, 256, 0, stream>>>(
        (const float*)d_in[6], (const float*)d_in[7],
        (const float*)d_in[8], (const float*)d_in[9], wq_e, bq_e);

    attn2<<<2 * NWIN, 256, 0, stream>>>(e_f, b_f,
        (const float*)d_in[2], (const float*)d_in[3],
        (const float*)d_in[4], (const float*)d_in[5],
        wq_e, bq_e, (const float*)d_in[14], wg_e,
        (const float*)d_in[11], (const float*)d_in[13], sige, oute);

    proj_mlp<<<2 * MROWS / 64, 256, 0, stream>>>(oute, outb, sige, wp_e,
        (const float*)d_in[16], (const float*)d_in[18], e_f, b_f,
        (const float*)d_in[19], (const float*)d_in[20],
        (const float*)d_in[21], (const float*)d_in[22],
        w1_e, (const float*)d_in[24], (const float*)d_in[28],
        w2_e, (const float*)d_in[26], (const float*)d_in[30], stats, xe);
}